// Round 1
// baseline (1019.733 us; speedup 1.0000x reference)
//
#include <hip/hip_runtime.h>

#define NNODE  100000
#define NEDGE  500000
#define NG     1024
#define DD     128
#define HH     512
#define PPART  8      // privatized partial accumulators for edge scatter
#define GB     8      // graphs per block in fused MLP kernel

// ---- index helper: handles both int32 and int64 index buffers ----
__device__ __forceinline__ int load_idx(const int* p, long long i, bool is64) {
    if (is64) return (int)(((const long long*)p)[i]);
    return p[i];
}

// Detect whether "int" inputs are really int64: batch is sorted with max ~1023,
// so if stored as int64, int32 word [NNODE-1] (odd index -> high word) is 0.
// If stored as int32, batch[NNODE-1] is the max graph id (>0).
__device__ __forceinline__ bool detect_i64(const int* batch_raw) {
    return batch_raw[NNODE - 1] == 0;
}

// ---------------- Kernel A: edge scatter-sum (privatized atomics) -------------
__global__ __launch_bounds__(256)
void edge_scatter(const float* __restrict__ ea,
                  const int*   __restrict__ eidx,   // row 0 = src nodes
                  const int*   __restrict__ batch,
                  float* __restrict__ part,         // [PPART][NG][DD]
                  float* __restrict__ pcnt)         // [PPART][NG]
{
    const bool is64 = detect_i64(batch);
    const long long total = (long long)NEDGE * 32;
    const int p = blockIdx.x & (PPART - 1);
    float* ps = part + (size_t)p * NG * DD;
    float* pc = pcnt + (size_t)p * NG;

    for (long long i = (long long)blockIdx.x * blockDim.x + threadIdx.x;
         i < total; i += (long long)gridDim.x * blockDim.x) {
        const int e = (int)(i >> 5);
        const int q = (int)(i & 31);
        const int s = load_idx(eidx, e, is64);        // src node of edge e
        const int g = load_idx(batch, s, is64);       // graph id
        const float4 v = *reinterpret_cast<const float4*>(ea + (size_t)e * DD + q * 4);
        float* dst = ps + (size_t)g * DD + q * 4;
        atomicAdd(dst + 0, v.x);
        atomicAdd(dst + 1, v.y);
        atomicAdd(dst + 2, v.z);
        atomicAdd(dst + 3, v.w);
        if (q == 0) atomicAdd(pc + g, 1.0f);
    }
}

// ---------------- Kernel B: node mean via sorted-batch binary search ----------
__global__ __launch_bounds__(128)
void node_mean_kernel(const float* __restrict__ x,
                      const int*   __restrict__ batch,
                      float* __restrict__ nmean)      // [NG][DD]
{
    const bool is64 = detect_i64(batch);
    const int g = blockIdx.x;
    __shared__ int sh[2];
    if (threadIdx.x == 0) {
        int lo = 0, hi = NNODE;
        while (lo < hi) { int mid = (lo + hi) >> 1;
                          if (load_idx(batch, mid, is64) < g) lo = mid + 1; else hi = mid; }
        sh[0] = lo;
        hi = NNODE;
        while (lo < hi) { int mid = (lo + hi) >> 1;
                          if (load_idx(batch, mid, is64) < g + 1) lo = mid + 1; else hi = mid; }
        sh[1] = lo;
    }
    __syncthreads();
    const int start = sh[0], end = sh[1];
    float s = 0.f;
    for (int r = start; r < end; ++r)
        s += x[(size_t)r * DD + threadIdx.x];
    const float cnt = (float)(end - start);
    nmean[(size_t)g * DD + threadIdx.x] = s / fmaxf(cnt, 1.0f);
}

// ---------------- Kernel C: fused reduce + MLP + residual + LayerNorm ---------
__global__ __launch_bounds__(256)
void mlp_ln(const float* __restrict__ u,
            const float* __restrict__ W1, const float* __restrict__ b1,
            const float* __restrict__ W2, const float* __restrict__ b2,
            const float* __restrict__ gamma, const float* __restrict__ beta,
            const float* __restrict__ part, const float* __restrict__ pcnt,
            const float* __restrict__ nmean, float* __restrict__ out)
{
    __shared__ float xin[GB][3 * DD];   // 12 KB
    __shared__ float hbuf[GB][HH];      // 16 KB
    __shared__ float ecnt_s[GB];
    __shared__ float psum[4][4], psq[4][4];

    const int g0 = blockIdx.x * GB;
    const int tid = threadIdx.x;

    if (tid < GB) {
        float c = 0.f;
        for (int p = 0; p < PPART; ++p) c += pcnt[(size_t)p * NG + g0 + tid];
        ecnt_s[tid] = fmaxf(c, 1.0f);
    }
    __syncthreads();

    // stage concat([u, edge_mean, node_mean]) into LDS
    for (int idx = tid; idx < GB * 3 * DD; idx += 256) {
        const int g = idx / (3 * DD);
        const int k = idx % (3 * DD);
        float v;
        if (k < DD) {
            v = u[(size_t)(g0 + g) * DD + k];
        } else if (k < 2 * DD) {
            const int q = k - DD;
            float s = 0.f;
            for (int p = 0; p < PPART; ++p)
                s += part[((size_t)p * NG + g0 + g) * DD + q];
            v = s / ecnt_s[g];
        } else {
            v = nmean[(size_t)(g0 + g) * DD + (k - 2 * DD)];
        }
        xin[g][k] = v;
    }
    __syncthreads();

    // phase 1: hidden = relu(xin @ W1 + b1), each thread does 2 hidden units x 8 graphs
    for (int jj = 0; jj < HH; jj += 256) {
        const int j = jj + tid;
        float acc[GB];
        const float bb = b1[j];
        #pragma unroll
        for (int g = 0; g < GB; ++g) acc[g] = bb;
        for (int k = 0; k < 3 * DD; k += 4) {
            const float w0 = W1[(size_t)(k + 0) * HH + j];
            const float w1 = W1[(size_t)(k + 1) * HH + j];
            const float w2 = W1[(size_t)(k + 2) * HH + j];
            const float w3 = W1[(size_t)(k + 3) * HH + j];
            #pragma unroll
            for (int g = 0; g < GB; ++g) {
                const float4 xv = *reinterpret_cast<const float4*>(&xin[g][k]);
                acc[g] = fmaf(xv.x, w0, acc[g]);
                acc[g] = fmaf(xv.y, w1, acc[g]);
                acc[g] = fmaf(xv.z, w2, acc[g]);
                acc[g] = fmaf(xv.w, w3, acc[g]);
            }
        }
        #pragma unroll
        for (int g = 0; g < GB; ++g) hbuf[g][j] = fmaxf(acc[g], 0.f);
    }
    __syncthreads();

    // phase 2: y = hbuf @ W2 + b2; r = y + u; layernorm(r)
    const int half = tid >> 7;     // 0: graphs 0..3, 1: graphs 4..7
    const int d = tid & 127;
    float acc2[4];
    const float bb2 = b2[d];
    #pragma unroll
    for (int gg = 0; gg < 4; ++gg) acc2[gg] = bb2;
    for (int j = 0; j < HH; j += 4) {
        const float w0 = W2[(size_t)(j + 0) * DD + d];
        const float w1 = W2[(size_t)(j + 1) * DD + d];
        const float w2 = W2[(size_t)(j + 2) * DD + d];
        const float w3 = W2[(size_t)(j + 3) * DD + d];
        #pragma unroll
        for (int gg = 0; gg < 4; ++gg) {
            const float4 hv = *reinterpret_cast<const float4*>(&hbuf[half * 4 + gg][j]);
            acc2[gg] = fmaf(hv.x, w0, acc2[gg]);
            acc2[gg] = fmaf(hv.y, w1, acc2[gg]);
            acc2[gg] = fmaf(hv.z, w2, acc2[gg]);
            acc2[gg] = fmaf(hv.w, w3, acc2[gg]);
        }
    }

    float r[4], s1[4], s2[4];
    #pragma unroll
    for (int gg = 0; gg < 4; ++gg) {
        r[gg] = acc2[gg] + u[(size_t)(g0 + half * 4 + gg) * DD + d];
        s1[gg] = r[gg];
        s2[gg] = r[gg] * r[gg];
    }
    // per-wave (64-lane) reduce
    #pragma unroll
    for (int off = 32; off >= 1; off >>= 1) {
        #pragma unroll
        for (int gg = 0; gg < 4; ++gg) {
            s1[gg] += __shfl_xor(s1[gg], off, 64);
            s2[gg] += __shfl_xor(s2[gg], off, 64);
        }
    }
    const int wave = tid >> 6;  // 0..3; waves {0,1} = half 0, {2,3} = half 1
    if ((tid & 63) == 0) {
        #pragma unroll
        for (int gg = 0; gg < 4; ++gg) { psum[wave][gg] = s1[gg]; psq[wave][gg] = s2[gg]; }
    }
    __syncthreads();
    #pragma unroll
    for (int gg = 0; gg < 4; ++gg) {
        const float tot  = psum[half * 2][gg] + psum[half * 2 + 1][gg];
        const float tot2 = psq [half * 2][gg] + psq [half * 2 + 1][gg];
        const float mu   = tot * (1.0f / DD);
        const float var  = tot2 * (1.0f / DD) - mu * mu;
        const float inv  = rsqrtf(var + 1e-5f);
        const float y    = (r[gg] - mu) * inv * gamma[d] + beta[d];
        out[(size_t)(g0 + half * 4 + gg) * DD + d] = y;
    }
}

extern "C" void kernel_launch(void* const* d_in, const int* in_sizes, int n_in,
                              void* d_out, int out_size, void* d_ws, size_t ws_size,
                              hipStream_t stream) {
    const float* x     = (const float*)d_in[0];
    const float* ea    = (const float*)d_in[1];
    const float* u     = (const float*)d_in[2];
    const float* W1    = (const float*)d_in[3];
    const float* b1    = (const float*)d_in[4];
    const float* W2    = (const float*)d_in[5];
    const float* b2    = (const float*)d_in[6];
    const float* gamma = (const float*)d_in[7];
    const float* beta  = (const float*)d_in[8];
    const int*   eidx  = (const int*)d_in[9];
    const int*   batch = (const int*)d_in[10];
    float* out = (float*)d_out;

    float* ws    = (float*)d_ws;
    float* part  = ws;                                   // PPART*NG*DD
    float* pcnt  = part + (size_t)PPART * NG * DD;       // PPART*NG
    float* nmean = pcnt + (size_t)PPART * NG;            // NG*DD

    const size_t zero_bytes = ((size_t)PPART * NG * DD + (size_t)PPART * NG) * sizeof(float);
    hipMemsetAsync(d_ws, 0, zero_bytes, stream);

    edge_scatter<<<4096, 256, 0, stream>>>(ea, eidx, batch, part, pcnt);
    node_mean_kernel<<<NG, 128, 0, stream>>>(x, batch, nmean);
    mlp_ln<<<NG / GB, 256, 0, stream>>>(u, W1, b1, W2, b2, gamma, beta,
                                        part, pcnt, nmean, out);
}

// Round 2
// 309.918 us; speedup vs baseline: 3.2903x; 3.2903x over previous
//
#include <hip/hip_runtime.h>

#define NNODE  100000
#define NEDGE  500000
#define NG     1024
#define DD     128
#define HH     512
#define GB     8      // graphs per block in fused MLP kernel

// ---- index helper: handles both int32 and int64 index buffers ----
__device__ __forceinline__ int load_idx(const int* p, long long i, bool is64) {
    if (is64) return (int)(((const long long*)p)[i]);
    return p[i];
}

// batch is sorted, max ~1023. If stored as int64, int32 word [NNODE-1] (odd
// index -> high word of element 49999) is 0. If int32, it's the max id (>0).
__device__ __forceinline__ bool detect_i64(const int* batch_raw) {
    return batch_raw[NNODE - 1] == 0;
}

// ---------------- S1: per-edge graph id + LDS-privatized histogram -----------
__global__ __launch_bounds__(256)
void hist_kernel(const int* __restrict__ eidx,
                 const int* __restrict__ batch,
                 unsigned short* __restrict__ g_e,
                 int* __restrict__ count)
{
    __shared__ int lcount[NG];
    for (int i = threadIdx.x; i < NG; i += blockDim.x) lcount[i] = 0;
    __syncthreads();
    const bool is64 = detect_i64(batch);
    for (int e = blockIdx.x * blockDim.x + threadIdx.x; e < NEDGE;
         e += gridDim.x * blockDim.x) {
        const int s = load_idx(eidx, e, is64);
        const int g = load_idx(batch, s, is64);
        g_e[e] = (unsigned short)g;
        atomicAdd(&lcount[g], 1);
    }
    __syncthreads();
    for (int i = threadIdx.x; i < NG; i += blockDim.x)
        if (lcount[i]) atomicAdd(&count[i], lcount[i]);
}

// ---------------- S2: exclusive scan of 1024 counts (single block) -----------
__global__ __launch_bounds__(1024)
void scan1024(const int* __restrict__ count,
              int* __restrict__ offset, int* __restrict__ cursor)
{
    __shared__ int buf[NG];
    const int t = threadIdx.x;
    const int v = count[t];
    int sum = v;
    buf[t] = v;
    __syncthreads();
    for (int off = 1; off < NG; off <<= 1) {
        const int add = (t >= off) ? buf[t - off] : 0;
        __syncthreads();
        sum += add;
        buf[t] = sum;
        __syncthreads();
    }
    offset[t] = sum - v;
    cursor[t] = sum - v;
}

// ---------------- S3: bucket edge ids by graph --------------------------------
__global__ __launch_bounds__(256)
void scatter_ids(const unsigned short* __restrict__ g_e,
                 int* __restrict__ cursor, int* __restrict__ perm)
{
    for (int e = blockIdx.x * blockDim.x + threadIdx.x; e < NEDGE;
         e += gridDim.x * blockDim.x) {
        const int g = g_e[e];
        const int pos = atomicAdd(&cursor[g], 1);
        perm[pos] = e;
    }
}

// ---------------- S4: gather-sum edge rows per graph --------------------------
__global__ __launch_bounds__(256)
void edge_gather_mean(const float* __restrict__ ea,
                      const int* __restrict__ perm,
                      const int* __restrict__ offset,
                      const int* __restrict__ count,
                      float* __restrict__ edge_mean)
{
    const int g = blockIdx.x;
    const int slot = threadIdx.x >> 7;    // 0,1
    const int d = threadIdx.x & 127;
    const int start = offset[g];
    const int n = count[g];
    const int end = start + n;
    float a0 = 0.f, a1 = 0.f, a2 = 0.f, a3 = 0.f;
    int i = start + slot;
    for (; i + 6 < end; i += 8) {
        const int e0 = perm[i];
        const int e1 = perm[i + 2];
        const int e2 = perm[i + 4];
        const int e3 = perm[i + 6];
        a0 += ea[(size_t)e0 * DD + d];
        a1 += ea[(size_t)e1 * DD + d];
        a2 += ea[(size_t)e2 * DD + d];
        a3 += ea[(size_t)e3 * DD + d];
    }
    for (; i < end; i += 2) a0 += ea[(size_t)perm[i] * DD + d];
    float s = (a0 + a1) + (a2 + a3);
    __shared__ float tmp[DD];
    if (slot == 1) tmp[d] = s;
    __syncthreads();
    if (slot == 0) {
        s += tmp[d];
        edge_mean[(size_t)g * DD + d] = s / fmaxf((float)n, 1.0f);
    }
}

// ---------------- node mean via sorted-batch binary search --------------------
__global__ __launch_bounds__(256)
void node_mean_kernel(const float* __restrict__ x,
                      const int* __restrict__ batch,
                      float* __restrict__ nmean)
{
    const bool is64 = detect_i64(batch);
    const int g = blockIdx.x;
    __shared__ int sh[2];
    if (threadIdx.x == 0) {
        int lo = 0, hi = NNODE;
        while (lo < hi) { int mid = (lo + hi) >> 1;
                          if (load_idx(batch, mid, is64) < g) lo = mid + 1; else hi = mid; }
        sh[0] = lo;
        hi = NNODE;
        while (lo < hi) { int mid = (lo + hi) >> 1;
                          if (load_idx(batch, mid, is64) < g + 1) lo = mid + 1; else hi = mid; }
        sh[1] = lo;
    }
    __syncthreads();
    const int start = sh[0], end = sh[1];
    const int slot = threadIdx.x >> 7;
    const int d = threadIdx.x & 127;
    float a0 = 0.f, a1 = 0.f, a2 = 0.f, a3 = 0.f;
    int i = start + slot;
    for (; i + 6 < end; i += 8) {
        a0 += x[(size_t)(i + 0) * DD + d];
        a1 += x[(size_t)(i + 2) * DD + d];
        a2 += x[(size_t)(i + 4) * DD + d];
        a3 += x[(size_t)(i + 6) * DD + d];
    }
    for (; i < end; i += 2) a0 += x[(size_t)i * DD + d];
    float s = (a0 + a1) + (a2 + a3);
    __shared__ float tmp[DD];
    if (slot == 1) tmp[d] = s;
    __syncthreads();
    if (slot == 0) {
        s += tmp[d];
        const float cnt = (float)(end - start);
        nmean[(size_t)g * DD + d] = s / fmaxf(cnt, 1.0f);
    }
}

// ---------------- fused MLP + residual + LayerNorm ----------------------------
__global__ __launch_bounds__(256)
void mlp_ln(const float* __restrict__ u,
            const float* __restrict__ W1, const float* __restrict__ b1,
            const float* __restrict__ W2, const float* __restrict__ b2,
            const float* __restrict__ gamma, const float* __restrict__ beta,
            const float* __restrict__ edge_mean,
            const float* __restrict__ nmean, float* __restrict__ out)
{
    __shared__ float xin[GB][3 * DD];   // 12 KB
    __shared__ float hbuf[GB][HH];      // 16 KB
    __shared__ float psum[4][4], psq[4][4];

    const int g0 = blockIdx.x * GB;
    const int tid = threadIdx.x;

    // stage concat([u, edge_mean, node_mean]) into LDS
    for (int idx = tid; idx < GB * 3 * DD; idx += 256) {
        const int g = idx / (3 * DD);
        const int k = idx % (3 * DD);
        float v;
        if (k < DD)           v = u[(size_t)(g0 + g) * DD + k];
        else if (k < 2 * DD)  v = edge_mean[(size_t)(g0 + g) * DD + (k - DD)];
        else                  v = nmean[(size_t)(g0 + g) * DD + (k - 2 * DD)];
        xin[g][k] = v;
    }
    __syncthreads();

    // phase 1: hidden = relu(xin @ W1 + b1)
    for (int jj = 0; jj < HH; jj += 256) {
        const int j = jj + tid;
        float acc[GB];
        const float bb = b1[j];
        #pragma unroll
        for (int g = 0; g < GB; ++g) acc[g] = bb;
        for (int k = 0; k < 3 * DD; k += 4) {
            const float w0 = W1[(size_t)(k + 0) * HH + j];
            const float w1 = W1[(size_t)(k + 1) * HH + j];
            const float w2 = W1[(size_t)(k + 2) * HH + j];
            const float w3 = W1[(size_t)(k + 3) * HH + j];
            #pragma unroll
            for (int g = 0; g < GB; ++g) {
                const float4 xv = *reinterpret_cast<const float4*>(&xin[g][k]);
                acc[g] = fmaf(xv.x, w0, acc[g]);
                acc[g] = fmaf(xv.y, w1, acc[g]);
                acc[g] = fmaf(xv.z, w2, acc[g]);
                acc[g] = fmaf(xv.w, w3, acc[g]);
            }
        }
        #pragma unroll
        for (int g = 0; g < GB; ++g) hbuf[g][j] = fmaxf(acc[g], 0.f);
    }
    __syncthreads();

    // phase 2: y = hbuf @ W2 + b2; r = y + u; layernorm(r)
    const int half = tid >> 7;
    const int d = tid & 127;
    float acc2[4];
    const float bb2 = b2[d];
    #pragma unroll
    for (int gg = 0; gg < 4; ++gg) acc2[gg] = bb2;
    for (int j = 0; j < HH; j += 4) {
        const float w0 = W2[(size_t)(j + 0) * DD + d];
        const float w1 = W2[(size_t)(j + 1) * DD + d];
        const float w2 = W2[(size_t)(j + 2) * DD + d];
        const float w3 = W2[(size_t)(j + 3) * DD + d];
        #pragma unroll
        for (int gg = 0; gg < 4; ++gg) {
            const float4 hv = *reinterpret_cast<const float4*>(&hbuf[half * 4 + gg][j]);
            acc2[gg] = fmaf(hv.x, w0, acc2[gg]);
            acc2[gg] = fmaf(hv.y, w1, acc2[gg]);
            acc2[gg] = fmaf(hv.z, w2, acc2[gg]);
            acc2[gg] = fmaf(hv.w, w3, acc2[gg]);
        }
    }

    float r[4], s1[4], s2[4];
    #pragma unroll
    for (int gg = 0; gg < 4; ++gg) {
        r[gg] = acc2[gg] + u[(size_t)(g0 + half * 4 + gg) * DD + d];
        s1[gg] = r[gg];
        s2[gg] = r[gg] * r[gg];
    }
    #pragma unroll
    for (int off = 32; off >= 1; off >>= 1) {
        #pragma unroll
        for (int gg = 0; gg < 4; ++gg) {
            s1[gg] += __shfl_xor(s1[gg], off, 64);
            s2[gg] += __shfl_xor(s2[gg], off, 64);
        }
    }
    const int wave = tid >> 6;
    if ((tid & 63) == 0) {
        #pragma unroll
        for (int gg = 0; gg < 4; ++gg) { psum[wave][gg] = s1[gg]; psq[wave][gg] = s2[gg]; }
    }
    __syncthreads();
    #pragma unroll
    for (int gg = 0; gg < 4; ++gg) {
        const float tot  = psum[half * 2][gg] + psum[half * 2 + 1][gg];
        const float tot2 = psq [half * 2][gg] + psq [half * 2 + 1][gg];
        const float mu   = tot * (1.0f / DD);
        const float var  = tot2 * (1.0f / DD) - mu * mu;
        const float inv  = rsqrtf(var + 1e-5f);
        const float y    = (r[gg] - mu) * inv * gamma[d] + beta[d];
        out[(size_t)(g0 + half * 4 + gg) * DD + d] = y;
    }
}

extern "C" void kernel_launch(void* const* d_in, const int* in_sizes, int n_in,
                              void* d_out, int out_size, void* d_ws, size_t ws_size,
                              hipStream_t stream) {
    const float* x     = (const float*)d_in[0];
    const float* ea    = (const float*)d_in[1];
    const float* u     = (const float*)d_in[2];
    const float* W1    = (const float*)d_in[3];
    const float* b1    = (const float*)d_in[4];
    const float* W2    = (const float*)d_in[5];
    const float* b2    = (const float*)d_in[6];
    const float* gamma = (const float*)d_in[7];
    const float* beta  = (const float*)d_in[8];
    const int*   eidx  = (const int*)d_in[9];
    const int*   batch = (const int*)d_in[10];
    float* out = (float*)d_out;

    float* ws        = (float*)d_ws;
    float* edge_mean = ws;                                   // NG*DD
    float* nmean     = edge_mean + (size_t)NG * DD;          // NG*DD
    unsigned short* g_e = (unsigned short*)(nmean + (size_t)NG * DD);  // NEDGE u16
    int*   count  = (int*)(g_e + NEDGE);                     // NG
    int*   offset = count + NG;                              // NG
    int*   cursor = offset + NG;                             // NG
    int*   perm   = cursor + NG;                             // NEDGE

    hipMemsetAsync(count, 0, NG * sizeof(int), stream);

    hist_kernel<<<240, 256, 0, stream>>>(eidx, batch, g_e, count);
    scan1024<<<1, 1024, 0, stream>>>(count, offset, cursor);
    scatter_ids<<<240, 256, 0, stream>>>(g_e, cursor, perm);
    edge_gather_mean<<<NG, 256, 0, stream>>>(ea, perm, offset, count, edge_mean);
    node_mean_kernel<<<NG, 256, 0, stream>>>(x, batch, nmean);
    mlp_ln<<<NG / GB, 256, 0, stream>>>(u, W1, b1, W2, b2, gamma, beta,
                                        edge_mean, nmean, out);
}

// Round 3
// 176.632 us; speedup vs baseline: 5.7732x; 1.7546x over previous
//
#include <hip/hip_runtime.h>

#define NNODE  100000
#define NEDGE  500000
#define NG     1024
#define DD     128
#define HH     512
#define GB     8        // graphs per block in fused MLP kernel
#define BCH    128      // counting-sort blocks
#define CHUNK  ((NEDGE + BCH - 1) / BCH)   // 3907 edges per block

// ---- index helper: handles both int32 and int64 index buffers ----
__device__ __forceinline__ int load_idx(const int* p, long long i, bool is64) {
    if (is64) return (int)(((const long long*)p)[i]);
    return p[i];
}

// batch is sorted, max ~1023. If stored as int64, int32 word [NNODE-1] (odd
// index -> high word) is 0. If int32, it's the max graph id (>0).
__device__ __forceinline__ bool detect_i64(const int* batch_raw) {
    return batch_raw[NNODE - 1] == 0;
}

// ---- P1: per-block histogram + per-edge graph id (no global atomics) --------
__global__ __launch_bounds__(256)
void hist_kernel(const int* __restrict__ eidx,
                 const int* __restrict__ batch,
                 unsigned short* __restrict__ g_e,
                 int* __restrict__ bh)            // [BCH][NG]
{
    __shared__ int lh[NG];
    for (int i = threadIdx.x; i < NG; i += 256) lh[i] = 0;
    __syncthreads();
    const bool is64 = detect_i64(batch);
    const int c0 = blockIdx.x * CHUNK;
    const int c1 = min(c0 + CHUNK, NEDGE);
    for (int e = c0 + threadIdx.x; e < c1; e += 256) {
        const int s = load_idx(eidx, e, is64);
        const int g = load_idx(batch, s, is64);
        g_e[e] = (unsigned short)g;
        atomicAdd(&lh[g], 1);
    }
    __syncthreads();
    int* row = bh + (size_t)blockIdx.x * NG;
    for (int i = threadIdx.x; i < NG; i += 256) row[i] = lh[i];
}

// ---- P2a: column totals: count[g] = sum_b bh[b][g] ---------------------------
__global__ __launch_bounds__(256)
void tot_kernel(const int* __restrict__ bh, int* __restrict__ count)
{
    const int g = blockIdx.x * 256 + threadIdx.x;
    int s = 0;
    for (int b = 0; b < BCH; ++b) s += bh[(size_t)b * NG + g];
    count[g] = s;
}

// ---- P2b: exclusive scan of 1024 counts (single block) -----------------------
__global__ __launch_bounds__(1024)
void scan1024(const int* __restrict__ count, int* __restrict__ offset)
{
    __shared__ int buf[NG];
    const int t = threadIdx.x;
    const int v = count[t];
    int sum = v;
    buf[t] = v;
    __syncthreads();
    for (int off = 1; off < NG; off <<= 1) {
        const int add = (t >= off) ? buf[t - off] : 0;
        __syncthreads();
        sum += add;
        buf[t] = sum;
        __syncthreads();
    }
    offset[t] = sum - v;
}

// ---- P2c: base[b][g] = offset[g] + prefix over blocks ------------------------
__global__ __launch_bounds__(256)
void mkbase_kernel(const int* __restrict__ bh, const int* __restrict__ offset,
                   int* __restrict__ base)
{
    const int g = blockIdx.x * 256 + threadIdx.x;
    int run = offset[g];
    for (int b = 0; b < BCH; ++b) {
        const int c = bh[(size_t)b * NG + g];
        base[(size_t)b * NG + g] = run;     // coalesced across g
        run += c;
    }
}

// ---- P3: place edge ids (LDS rank counters only) -----------------------------
__global__ __launch_bounds__(256)
void scatter_ids(const unsigned short* __restrict__ g_e,
                 const int* __restrict__ base, int* __restrict__ perm)
{
    __shared__ int lb[NG];
    const int* brow = base + (size_t)blockIdx.x * NG;
    for (int i = threadIdx.x; i < NG; i += 256) lb[i] = brow[i];
    __syncthreads();
    const int c0 = blockIdx.x * CHUNK;
    const int c1 = min(c0 + CHUNK, NEDGE);
    for (int e = c0 + threadIdx.x; e < c1; e += 256) {
        const int g = g_e[e];
        const int pos = atomicAdd(&lb[g], 1);   // LDS atomic
        perm[pos] = e;
    }
}

// ---- P4: fused edge gather-mean (blocks 0..NG-1) + node mean (NG..2NG-1) ------
__global__ __launch_bounds__(256)
void gather_means(const float* __restrict__ ea,
                  const float* __restrict__ x,
                  const int* __restrict__ perm,
                  const int* __restrict__ offset,
                  const int* __restrict__ count,
                  const int* __restrict__ batch,
                  float* __restrict__ edge_mean,
                  float* __restrict__ nmean)
{
    const int q = threadIdx.x & 31;     // 4-dim chunk: dims [4q, 4q+4)
    const int slot = threadIdx.x >> 5;  // 0..7 row slots
    __shared__ float4 red[8][32];

    if (blockIdx.x < NG) {
        // ---------------- edge mean for graph g ----------------
        const int g = blockIdx.x;
        const int start = offset[g];
        const int n = count[g];
        const int end = start + n;
        float4 a0 = {0,0,0,0}, a1 = {0,0,0,0}, a2 = {0,0,0,0}, a3 = {0,0,0,0};
        int i = start + slot;
        for (; i + 24 < end; i += 32) {
            const int e0 = perm[i];
            const int e1 = perm[i + 8];
            const int e2 = perm[i + 16];
            const int e3 = perm[i + 24];
            const float4 v0 = *reinterpret_cast<const float4*>(ea + (size_t)e0 * DD + q * 4);
            const float4 v1 = *reinterpret_cast<const float4*>(ea + (size_t)e1 * DD + q * 4);
            const float4 v2 = *reinterpret_cast<const float4*>(ea + (size_t)e2 * DD + q * 4);
            const float4 v3 = *reinterpret_cast<const float4*>(ea + (size_t)e3 * DD + q * 4);
            a0.x += v0.x; a0.y += v0.y; a0.z += v0.z; a0.w += v0.w;
            a1.x += v1.x; a1.y += v1.y; a1.z += v1.z; a1.w += v1.w;
            a2.x += v2.x; a2.y += v2.y; a2.z += v2.z; a2.w += v2.w;
            a3.x += v3.x; a3.y += v3.y; a3.z += v3.z; a3.w += v3.w;
        }
        for (; i < end; i += 8) {
            const float4 v = *reinterpret_cast<const float4*>(ea + (size_t)perm[i] * DD + q * 4);
            a0.x += v.x; a0.y += v.y; a0.z += v.z; a0.w += v.w;
        }
        float4 acc;
        acc.x = (a0.x + a1.x) + (a2.x + a3.x);
        acc.y = (a0.y + a1.y) + (a2.y + a3.y);
        acc.z = (a0.z + a1.z) + (a2.z + a3.z);
        acc.w = (a0.w + a1.w) + (a2.w + a3.w);
        red[slot][q] = acc;
        __syncthreads();
        if (slot == 0) {
            #pragma unroll
            for (int s = 1; s < 8; ++s) {
                const float4 v = red[s][q];
                acc.x += v.x; acc.y += v.y; acc.z += v.z; acc.w += v.w;
            }
            const float inv = 1.0f / fmaxf((float)n, 1.0f);
            float4 m; m.x = acc.x * inv; m.y = acc.y * inv; m.z = acc.z * inv; m.w = acc.w * inv;
            *reinterpret_cast<float4*>(edge_mean + (size_t)g * DD + q * 4) = m;
        }
    } else {
        // ---------------- node mean for graph g ----------------
        const bool is64 = detect_i64(batch);
        const int g = blockIdx.x - NG;
        __shared__ int sh[2];
        if (threadIdx.x == 0) {
            int lo = 0, hi = NNODE;
            while (lo < hi) { int mid = (lo + hi) >> 1;
                              if (load_idx(batch, mid, is64) < g) lo = mid + 1; else hi = mid; }
            sh[0] = lo;
            hi = NNODE;
            while (lo < hi) { int mid = (lo + hi) >> 1;
                              if (load_idx(batch, mid, is64) < g + 1) lo = mid + 1; else hi = mid; }
            sh[1] = lo;
        }
        __syncthreads();
        const int start = sh[0], end = sh[1];
        float4 a0 = {0,0,0,0}, a1 = {0,0,0,0};
        int i = start + slot;
        for (; i + 8 < end; i += 16) {
            const float4 v0 = *reinterpret_cast<const float4*>(x + (size_t)i * DD + q * 4);
            const float4 v1 = *reinterpret_cast<const float4*>(x + (size_t)(i + 8) * DD + q * 4);
            a0.x += v0.x; a0.y += v0.y; a0.z += v0.z; a0.w += v0.w;
            a1.x += v1.x; a1.y += v1.y; a1.z += v1.z; a1.w += v1.w;
        }
        for (; i < end; i += 8) {
            const float4 v = *reinterpret_cast<const float4*>(x + (size_t)i * DD + q * 4);
            a0.x += v.x; a0.y += v.y; a0.z += v.z; a0.w += v.w;
        }
        float4 acc;
        acc.x = a0.x + a1.x; acc.y = a0.y + a1.y;
        acc.z = a0.z + a1.z; acc.w = a0.w + a1.w;
        red[slot][q] = acc;
        __syncthreads();
        if (slot == 0) {
            #pragma unroll
            for (int s = 1; s < 8; ++s) {
                const float4 v = red[s][q];
                acc.x += v.x; acc.y += v.y; acc.z += v.z; acc.w += v.w;
            }
            const float inv = 1.0f / fmaxf((float)(end - start), 1.0f);
            float4 m; m.x = acc.x * inv; m.y = acc.y * inv; m.z = acc.z * inv; m.w = acc.w * inv;
            *reinterpret_cast<float4*>(nmean + (size_t)g * DD + q * 4) = m;
        }
    }
}

// ---------------- fused MLP + residual + LayerNorm ----------------------------
__global__ __launch_bounds__(256)
void mlp_ln(const float* __restrict__ u,
            const float* __restrict__ W1, const float* __restrict__ b1,
            const float* __restrict__ W2, const float* __restrict__ b2,
            const float* __restrict__ gamma, const float* __restrict__ beta,
            const float* __restrict__ edge_mean,
            const float* __restrict__ nmean, float* __restrict__ out)
{
    __shared__ float xin[GB][3 * DD];   // 12 KB
    __shared__ float hbuf[GB][HH];      // 16 KB
    __shared__ float psum[4][4], psq[4][4];

    const int g0 = blockIdx.x * GB;
    const int tid = threadIdx.x;

    for (int idx = tid; idx < GB * 3 * DD; idx += 256) {
        const int g = idx / (3 * DD);
        const int k = idx % (3 * DD);
        float v;
        if (k < DD)           v = u[(size_t)(g0 + g) * DD + k];
        else if (k < 2 * DD)  v = edge_mean[(size_t)(g0 + g) * DD + (k - DD)];
        else                  v = nmean[(size_t)(g0 + g) * DD + (k - 2 * DD)];
        xin[g][k] = v;
    }
    __syncthreads();

    for (int jj = 0; jj < HH; jj += 256) {
        const int j = jj + tid;
        float acc[GB];
        const float bb = b1[j];
        #pragma unroll
        for (int g = 0; g < GB; ++g) acc[g] = bb;
        for (int k = 0; k < 3 * DD; k += 4) {
            const float w0 = W1[(size_t)(k + 0) * HH + j];
            const float w1 = W1[(size_t)(k + 1) * HH + j];
            const float w2 = W1[(size_t)(k + 2) * HH + j];
            const float w3 = W1[(size_t)(k + 3) * HH + j];
            #pragma unroll
            for (int g = 0; g < GB; ++g) {
                const float4 xv = *reinterpret_cast<const float4*>(&xin[g][k]);
                acc[g] = fmaf(xv.x, w0, acc[g]);
                acc[g] = fmaf(xv.y, w1, acc[g]);
                acc[g] = fmaf(xv.z, w2, acc[g]);
                acc[g] = fmaf(xv.w, w3, acc[g]);
            }
        }
        #pragma unroll
        for (int g = 0; g < GB; ++g) hbuf[g][j] = fmaxf(acc[g], 0.f);
    }
    __syncthreads();

    const int half = tid >> 7;
    const int d = tid & 127;
    float acc2[4];
    const float bb2 = b2[d];
    #pragma unroll
    for (int gg = 0; gg < 4; ++gg) acc2[gg] = bb2;
    for (int j = 0; j < HH; j += 4) {
        const float w0 = W2[(size_t)(j + 0) * DD + d];
        const float w1 = W2[(size_t)(j + 1) * DD + d];
        const float w2 = W2[(size_t)(j + 2) * DD + d];
        const float w3 = W2[(size_t)(j + 3) * DD + d];
        #pragma unroll
        for (int gg = 0; gg < 4; ++gg) {
            const float4 hv = *reinterpret_cast<const float4*>(&hbuf[half * 4 + gg][j]);
            acc2[gg] = fmaf(hv.x, w0, acc2[gg]);
            acc2[gg] = fmaf(hv.y, w1, acc2[gg]);
            acc2[gg] = fmaf(hv.z, w2, acc2[gg]);
            acc2[gg] = fmaf(hv.w, w3, acc2[gg]);
        }
    }

    float r[4], s1[4], s2[4];
    #pragma unroll
    for (int gg = 0; gg < 4; ++gg) {
        r[gg] = acc2[gg] + u[(size_t)(g0 + half * 4 + gg) * DD + d];
        s1[gg] = r[gg];
        s2[gg] = r[gg] * r[gg];
    }
    #pragma unroll
    for (int off = 32; off >= 1; off >>= 1) {
        #pragma unroll
        for (int gg = 0; gg < 4; ++gg) {
            s1[gg] += __shfl_xor(s1[gg], off, 64);
            s2[gg] += __shfl_xor(s2[gg], off, 64);
        }
    }
    const int wave = tid >> 6;
    if ((tid & 63) == 0) {
        #pragma unroll
        for (int gg = 0; gg < 4; ++gg) { psum[wave][gg] = s1[gg]; psq[wave][gg] = s2[gg]; }
    }
    __syncthreads();
    #pragma unroll
    for (int gg = 0; gg < 4; ++gg) {
        const float tot  = psum[half * 2][gg] + psum[half * 2 + 1][gg];
        const float tot2 = psq [half * 2][gg] + psq [half * 2 + 1][gg];
        const float mu   = tot * (1.0f / DD);
        const float var  = tot2 * (1.0f / DD) - mu * mu;
        const float inv  = rsqrtf(var + 1e-5f);
        const float y    = (r[gg] - mu) * inv * gamma[d] + beta[d];
        out[(size_t)(g0 + half * 4 + gg) * DD + d] = y;
    }
}

extern "C" void kernel_launch(void* const* d_in, const int* in_sizes, int n_in,
                              void* d_out, int out_size, void* d_ws, size_t ws_size,
                              hipStream_t stream) {
    const float* x     = (const float*)d_in[0];
    const float* ea    = (const float*)d_in[1];
    const float* u     = (const float*)d_in[2];
    const float* W1    = (const float*)d_in[3];
    const float* b1    = (const float*)d_in[4];
    const float* W2    = (const float*)d_in[5];
    const float* b2    = (const float*)d_in[6];
    const float* gamma = (const float*)d_in[7];
    const float* beta  = (const float*)d_in[8];
    const int*   eidx  = (const int*)d_in[9];
    const int*   batch = (const int*)d_in[10];
    float* out = (float*)d_out;

    float* ws        = (float*)d_ws;
    float* edge_mean = ws;                                    // NG*DD
    float* nmean     = edge_mean + (size_t)NG * DD;           // NG*DD
    unsigned short* g_e = (unsigned short*)(nmean + (size_t)NG * DD);  // NEDGE u16
    int* count  = (int*)(g_e + NEDGE);                        // NG
    int* offset = count + NG;                                 // NG
    int* bh     = offset + NG;                                // BCH*NG
    int* base   = bh + (size_t)BCH * NG;                      // BCH*NG
    int* perm   = base + (size_t)BCH * NG;                    // NEDGE

    hist_kernel<<<BCH, 256, 0, stream>>>(eidx, batch, g_e, bh);
    tot_kernel<<<NG / 256, 256, 0, stream>>>(bh, count);
    scan1024<<<1, 1024, 0, stream>>>(count, offset);
    mkbase_kernel<<<NG / 256, 256, 0, stream>>>(bh, offset, base);
    scatter_ids<<<BCH, 256, 0, stream>>>(g_e, base, perm);
    gather_means<<<2 * NG, 256, 0, stream>>>(ea, x, perm, offset, count, batch,
                                             edge_mean, nmean);
    mlp_ln<<<NG / GB, 256, 0, stream>>>(u, W1, b1, W2, b2, gamma, beta,
                                        edge_mean, nmean, out);
}

// Round 4
// 148.206 us; speedup vs baseline: 6.8805x; 1.1918x over previous
//
#include <hip/hip_runtime.h>

#define NNODE  100000
#define NEDGE  500000
#define NG     1024
#define DD     128
#define HH     512
#define GB     4        // graphs per block in fused MLP kernel
#define BCH    256      // counting-sort blocks
#define CHUNK  ((NEDGE + BCH - 1) / BCH)   // 1954 edges per block

// ---- index helper: handles both int32 and int64 index buffers ----
__device__ __forceinline__ int load_idx(const int* p, long long i, bool is64) {
    if (is64) return (int)(((const long long*)p)[i]);
    return p[i];
}

// batch is sorted, max ~1023. If stored as int64, int32 word [NNODE-1] (odd
// index -> high word) is 0. If int32, it's the max graph id (>0).
__device__ __forceinline__ bool detect_i64(const int* batch_raw) {
    return batch_raw[NNODE - 1] == 0;
}

// ---- K1: per-block edge histogram (blocks 0..BCH-1)  +  node means (rest) ---
__global__ __launch_bounds__(256)
void hist_node(const int* __restrict__ eidx,
               const int* __restrict__ batch,
               const float* __restrict__ x,
               unsigned short* __restrict__ g_e,
               int* __restrict__ bh,              // [BCH][NG]
               float* __restrict__ nmean)         // [NG][DD]
{
    const bool is64 = detect_i64(batch);
    if (blockIdx.x < BCH) {
        __shared__ int lh[NG];
        for (int i = threadIdx.x; i < NG; i += 256) lh[i] = 0;
        __syncthreads();
        const int c0 = blockIdx.x * CHUNK;
        const int c1 = min(c0 + CHUNK, NEDGE);
        for (int e = c0 + threadIdx.x; e < c1; e += 256) {
            const int s = load_idx(eidx, e, is64);
            const int g = load_idx(batch, s, is64);
            g_e[e] = (unsigned short)g;
            atomicAdd(&lh[g], 1);
        }
        __syncthreads();
        int* row = bh + (size_t)blockIdx.x * NG;
        for (int i = threadIdx.x; i < NG; i += 256) row[i] = lh[i];
    } else {
        // ---------------- node mean for graph g ----------------
        const int g = blockIdx.x - BCH;
        const int q = threadIdx.x & 31;     // dims [4q, 4q+4)
        const int slot = threadIdx.x >> 5;  // 0..7
        __shared__ int sh[2];
        __shared__ float4 red[8][32];
        if (threadIdx.x == 0) {
            int lo = 0, hi = NNODE;
            while (lo < hi) { int mid = (lo + hi) >> 1;
                              if (load_idx(batch, mid, is64) < g) lo = mid + 1; else hi = mid; }
            sh[0] = lo;
            hi = NNODE;
            while (lo < hi) { int mid = (lo + hi) >> 1;
                              if (load_idx(batch, mid, is64) < g + 1) lo = mid + 1; else hi = mid; }
            sh[1] = lo;
        }
        __syncthreads();
        const int start = sh[0], end = sh[1];
        float4 a0 = {0,0,0,0}, a1 = {0,0,0,0};
        int i = start + slot;
        for (; i + 8 < end; i += 16) {
            const float4 v0 = *reinterpret_cast<const float4*>(x + (size_t)i * DD + q * 4);
            const float4 v1 = *reinterpret_cast<const float4*>(x + (size_t)(i + 8) * DD + q * 4);
            a0.x += v0.x; a0.y += v0.y; a0.z += v0.z; a0.w += v0.w;
            a1.x += v1.x; a1.y += v1.y; a1.z += v1.z; a1.w += v1.w;
        }
        for (; i < end; i += 8) {
            const float4 v = *reinterpret_cast<const float4*>(x + (size_t)i * DD + q * 4);
            a0.x += v.x; a0.y += v.y; a0.z += v.z; a0.w += v.w;
        }
        float4 acc;
        acc.x = a0.x + a1.x; acc.y = a0.y + a1.y;
        acc.z = a0.z + a1.z; acc.w = a0.w + a1.w;
        red[slot][q] = acc;
        __syncthreads();
        if (slot == 0) {
            #pragma unroll
            for (int s = 1; s < 8; ++s) {
                const float4 v = red[s][q];
                acc.x += v.x; acc.y += v.y; acc.z += v.z; acc.w += v.w;
            }
            const float inv = 1.0f / fmaxf((float)(end - start), 1.0f);
            float4 m; m.x = acc.x * inv; m.y = acc.y * inv; m.z = acc.z * inv; m.w = acc.w * inv;
            *reinterpret_cast<float4*>(nmean + (size_t)g * DD + q * 4) = m;
        }
    }
}

// ---- K2: column totals + exclusive scan (single block, 1024 threads) --------
__global__ __launch_bounds__(1024)
void totscan(const int* __restrict__ bh,
             int* __restrict__ count, int* __restrict__ offset)
{
    __shared__ int buf[NG];
    const int t = threadIdx.x;
    int v = 0;
    for (int b = 0; b < BCH; ++b) v += bh[(size_t)b * NG + t];
    count[t] = v;
    int sum = v;
    buf[t] = v;
    __syncthreads();
    for (int off = 1; off < NG; off <<= 1) {
        const int add = (t >= off) ? buf[t - off] : 0;
        __syncthreads();
        sum += add;
        buf[t] = sum;
        __syncthreads();
    }
    offset[t] = sum - v;
}

// ---- K3: base[b][g] = offset[g] + prefix over blocks -------------------------
__global__ __launch_bounds__(256)
void mkbase_kernel(const int* __restrict__ bh, const int* __restrict__ offset,
                   int* __restrict__ base)
{
    const int g = blockIdx.x * 256 + threadIdx.x;
    int run = offset[g];
    for (int b = 0; b < BCH; ++b) {
        const int c = bh[(size_t)b * NG + g];
        base[(size_t)b * NG + g] = run;     // coalesced across g
        run += c;
    }
}

// ---- K4: place edge ids (LDS rank counters only) -----------------------------
__global__ __launch_bounds__(256)
void scatter_ids(const unsigned short* __restrict__ g_e,
                 const int* __restrict__ base, int* __restrict__ perm)
{
    __shared__ int lb[NG];
    const int* brow = base + (size_t)blockIdx.x * NG;
    for (int i = threadIdx.x; i < NG; i += 256) lb[i] = brow[i];
    __syncthreads();
    const int c0 = blockIdx.x * CHUNK;
    const int c1 = min(c0 + CHUNK, NEDGE);
    for (int e = c0 + threadIdx.x; e < c1; e += 256) {
        const int g = g_e[e];
        const int pos = atomicAdd(&lb[g], 1);   // LDS atomic
        perm[pos] = e;
    }
}

// ---- K5: gather-sum edge rows per graph (512 threads, 16 row slots) ----------
__global__ __launch_bounds__(512)
void edge_gather_mean(const float* __restrict__ ea,
                      const int* __restrict__ perm,
                      const int* __restrict__ offset,
                      const int* __restrict__ count,
                      float* __restrict__ edge_mean)
{
    const int g = blockIdx.x;
    const int q = threadIdx.x & 31;     // dims [4q, 4q+4)
    const int slot = threadIdx.x >> 5;  // 0..15
    __shared__ float4 red[16][32];

    const int start = offset[g];
    const int n = count[g];
    const int end = start + n;
    float4 a0 = {0,0,0,0}, a1 = {0,0,0,0}, a2 = {0,0,0,0}, a3 = {0,0,0,0};
    int i = start + slot;
    for (; i + 48 < end; i += 64) {
        const int e0 = perm[i];
        const int e1 = perm[i + 16];
        const int e2 = perm[i + 32];
        const int e3 = perm[i + 48];
        const float4 v0 = *reinterpret_cast<const float4*>(ea + (size_t)e0 * DD + q * 4);
        const float4 v1 = *reinterpret_cast<const float4*>(ea + (size_t)e1 * DD + q * 4);
        const float4 v2 = *reinterpret_cast<const float4*>(ea + (size_t)e2 * DD + q * 4);
        const float4 v3 = *reinterpret_cast<const float4*>(ea + (size_t)e3 * DD + q * 4);
        a0.x += v0.x; a0.y += v0.y; a0.z += v0.z; a0.w += v0.w;
        a1.x += v1.x; a1.y += v1.y; a1.z += v1.z; a1.w += v1.w;
        a2.x += v2.x; a2.y += v2.y; a2.z += v2.z; a2.w += v2.w;
        a3.x += v3.x; a3.y += v3.y; a3.z += v3.z; a3.w += v3.w;
    }
    for (; i < end; i += 16) {
        const float4 v = *reinterpret_cast<const float4*>(ea + (size_t)perm[i] * DD + q * 4);
        a0.x += v.x; a0.y += v.y; a0.z += v.z; a0.w += v.w;
    }
    float4 acc;
    acc.x = (a0.x + a1.x) + (a2.x + a3.x);
    acc.y = (a0.y + a1.y) + (a2.y + a3.y);
    acc.z = (a0.z + a1.z) + (a2.z + a3.z);
    acc.w = (a0.w + a1.w) + (a2.w + a3.w);
    red[slot][q] = acc;
    __syncthreads();
    if (slot == 0) {
        #pragma unroll
        for (int s = 1; s < 16; ++s) {
            const float4 v = red[s][q];
            acc.x += v.x; acc.y += v.y; acc.z += v.z; acc.w += v.w;
        }
        const float inv = 1.0f / fmaxf((float)n, 1.0f);
        float4 m; m.x = acc.x * inv; m.y = acc.y * inv; m.z = acc.z * inv; m.w = acc.w * inv;
        *reinterpret_cast<float4*>(edge_mean + (size_t)g * DD + q * 4) = m;
    }
}

// ---- K6: fused MLP + residual + LayerNorm (GB=4 -> 256 blocks) ----------------
__global__ __launch_bounds__(256)
void mlp_ln(const float* __restrict__ u,
            const float* __restrict__ W1, const float* __restrict__ b1,
            const float* __restrict__ W2, const float* __restrict__ b2,
            const float* __restrict__ gamma, const float* __restrict__ beta,
            const float* __restrict__ edge_mean,
            const float* __restrict__ nmean, float* __restrict__ out)
{
    __shared__ float xin[GB][3 * DD];   // 6 KB
    __shared__ float hbuf[GB][HH];      // 8 KB
    __shared__ float psum[4][2], psq[4][2];

    const int g0 = blockIdx.x * GB;
    const int tid = threadIdx.x;

    // stage concat([u, edge_mean, node_mean]) into LDS
    for (int idx = tid; idx < GB * 3 * DD; idx += 256) {
        const int g = idx / (3 * DD);
        const int k = idx % (3 * DD);
        float v;
        if (k < DD)           v = u[(size_t)(g0 + g) * DD + k];
        else if (k < 2 * DD)  v = edge_mean[(size_t)(g0 + g) * DD + (k - DD)];
        else                  v = nmean[(size_t)(g0 + g) * DD + (k - 2 * DD)];
        xin[g][k] = v;
    }
    __syncthreads();

    // phase 1: hidden = relu(xin @ W1 + b1)
    for (int jj = 0; jj < HH; jj += 256) {
        const int j = jj + tid;
        float acc[GB];
        const float bb = b1[j];
        #pragma unroll
        for (int g = 0; g < GB; ++g) acc[g] = bb;
        for (int k = 0; k < 3 * DD; k += 4) {
            const float w0 = W1[(size_t)(k + 0) * HH + j];
            const float w1 = W1[(size_t)(k + 1) * HH + j];
            const float w2 = W1[(size_t)(k + 2) * HH + j];
            const float w3 = W1[(size_t)(k + 3) * HH + j];
            #pragma unroll
            for (int g = 0; g < GB; ++g) {
                const float4 xv = *reinterpret_cast<const float4*>(&xin[g][k]);
                acc[g] = fmaf(xv.x, w0, acc[g]);
                acc[g] = fmaf(xv.y, w1, acc[g]);
                acc[g] = fmaf(xv.z, w2, acc[g]);
                acc[g] = fmaf(xv.w, w3, acc[g]);
            }
        }
        #pragma unroll
        for (int g = 0; g < GB; ++g) hbuf[g][j] = fmaxf(acc[g], 0.f);
    }
    __syncthreads();

    // phase 2: y = hbuf @ W2 + b2; r = y + u; layernorm(r)
    const int half = tid >> 7;          // 0: graphs g0+0..1, 1: graphs g0+2..3
    const int d = tid & 127;
    float acc2[2];
    const float bb2 = b2[d];
    #pragma unroll
    for (int gg = 0; gg < 2; ++gg) acc2[gg] = bb2;
    for (int j = 0; j < HH; j += 4) {
        const float w0 = W2[(size_t)(j + 0) * DD + d];
        const float w1 = W2[(size_t)(j + 1) * DD + d];
        const float w2 = W2[(size_t)(j + 2) * DD + d];
        const float w3 = W2[(size_t)(j + 3) * DD + d];
        #pragma unroll
        for (int gg = 0; gg < 2; ++gg) {
            const float4 hv = *reinterpret_cast<const float4*>(&hbuf[half * 2 + gg][j]);
            acc2[gg] = fmaf(hv.x, w0, acc2[gg]);
            acc2[gg] = fmaf(hv.y, w1, acc2[gg]);
            acc2[gg] = fmaf(hv.z, w2, acc2[gg]);
            acc2[gg] = fmaf(hv.w, w3, acc2[gg]);
        }
    }

    float r[2], s1[2], s2[2];
    #pragma unroll
    for (int gg = 0; gg < 2; ++gg) {
        r[gg] = acc2[gg] + u[(size_t)(g0 + half * 2 + gg) * DD + d];
        s1[gg] = r[gg];
        s2[gg] = r[gg] * r[gg];
    }
    #pragma unroll
    for (int off = 32; off >= 1; off >>= 1) {
        #pragma unroll
        for (int gg = 0; gg < 2; ++gg) {
            s1[gg] += __shfl_xor(s1[gg], off, 64);
            s2[gg] += __shfl_xor(s2[gg], off, 64);
        }
    }
    const int wave = tid >> 6;          // waves {0,1} = half 0, {2,3} = half 1
    if ((tid & 63) == 0) {
        #pragma unroll
        for (int gg = 0; gg < 2; ++gg) { psum[wave][gg] = s1[gg]; psq[wave][gg] = s2[gg]; }
    }
    __syncthreads();
    #pragma unroll
    for (int gg = 0; gg < 2; ++gg) {
        const float tot  = psum[half * 2][gg] + psum[half * 2 + 1][gg];
        const float tot2 = psq [half * 2][gg] + psq [half * 2 + 1][gg];
        const float mu   = tot * (1.0f / DD);
        const float var  = tot2 * (1.0f / DD) - mu * mu;
        const float inv  = rsqrtf(var + 1e-5f);
        const float y    = (r[gg] - mu) * inv * gamma[d] + beta[d];
        out[(size_t)(g0 + half * 2 + gg) * DD + d] = y;
    }
}

extern "C" void kernel_launch(void* const* d_in, const int* in_sizes, int n_in,
                              void* d_out, int out_size, void* d_ws, size_t ws_size,
                              hipStream_t stream) {
    const float* x     = (const float*)d_in[0];
    const float* ea    = (const float*)d_in[1];
    const float* u     = (const float*)d_in[2];
    const float* W1    = (const float*)d_in[3];
    const float* b1    = (const float*)d_in[4];
    const float* W2    = (const float*)d_in[5];
    const float* b2    = (const float*)d_in[6];
    const float* gamma = (const float*)d_in[7];
    const float* beta  = (const float*)d_in[8];
    const int*   eidx  = (const int*)d_in[9];
    const int*   batch = (const int*)d_in[10];
    float* out = (float*)d_out;

    float* ws        = (float*)d_ws;
    float* edge_mean = ws;                                    // NG*DD
    float* nmean     = edge_mean + (size_t)NG * DD;           // NG*DD
    unsigned short* g_e = (unsigned short*)(nmean + (size_t)NG * DD);  // NEDGE u16
    int* count  = (int*)(g_e + NEDGE);                        // NG
    int* offset = count + NG;                                 // NG
    int* bh     = offset + NG;                                // BCH*NG
    int* base   = bh + (size_t)BCH * NG;                      // BCH*NG
    int* perm   = base + (size_t)BCH * NG;                    // NEDGE

    hist_node<<<BCH + NG, 256, 0, stream>>>(eidx, batch, x, g_e, bh, nmean);
    totscan<<<1, 1024, 0, stream>>>(bh, count, offset);
    mkbase_kernel<<<NG / 256, 256, 0, stream>>>(bh, offset, base);
    scatter_ids<<<BCH, 256, 0, stream>>>(g_e, base, perm);
    edge_gather_mean<<<NG, 512, 0, stream>>>(ea, perm, offset, count, edge_mean);
    mlp_ln<<<NG / GB, 256, 0, stream>>>(u, W1, b1, W2, b2, gamma, beta,
                                        edge_mean, nmean, out);
}